// Round 1
// 2048.335 us; speedup vs baseline: 1.4026x; 1.4026x over previous
//
#include <hip/hip_runtime.h>
#include <hip/hip_bf16.h>
#include <hip/hip_fp16.h>

typedef unsigned short u16;
typedef unsigned int u32;

#define SS 256
#define BB 64
#define DMT 1024
#define DMA 100
#define DMV 512
#define DG 512
#define HID 256
#define NROWS (SS*BB)   // 16384
#define EPSV 1e-5f
#define OUTW 3684       // 4*512 + 1636

typedef __attribute__((ext_vector_type(8))) short v8s;
typedef __attribute__((ext_vector_type(4))) float v4f;
typedef _Float16 half2v __attribute__((ext_vector_type(2)));

__device__ inline u16 f2bf(float x){
    union { float f; u32 u; } v; v.f = x;
    u32 r = (v.u + 0x7FFFu + ((v.u >> 16) & 1u)) >> 16;
    return (u16)r;
}
__device__ inline float bf2f(u16 h){
    union { u32 u; float f; } v; v.u = ((u32)h) << 16;
    return v.f;
}
__device__ inline float dot2u(u32 a, u32 b, float acc){
    half2v ha = __builtin_bit_cast(half2v, a);
    half2v hb = __builtin_bit_cast(half2v, b);
    return __builtin_amdgcn_fdot2(ha, hb, acc, false);
}
__device__ inline float sigm(float x){ return 1.f / (1.f + __expf(-x)); }

// ---------------- LayerNorm stats: per (tensor, batch j) mean & rstd over S x D ----------------
__global__ __launch_bounds__(256) void ln_stats(const float* r1, const float* r2,
                                                const float* r3, const float* r4,
                                                float* mu, float* rs){
    int j  = blockIdx.x;     // 0..63
    int tt = blockIdx.y;     // 0..3
    const float* r = (tt == 0) ? r1 : (tt == 1) ? r2 : (tt == 2) ? r3 : r4;
    int tid = threadIdx.x;
    float s = 0.f, s2 = 0.f;
    for (int t = 0; t < SS; t++){
        const float4* row = (const float4*)(r + (size_t)(t * BB + j) * DMT);
        float4 v = row[tid];
        s  += v.x + v.y + v.z + v.w;
        s2 += v.x*v.x + v.y*v.y + v.z*v.z + v.w*v.w;
    }
    // wave reduce (64) then cross-wave via LDS
    for (int off = 32; off > 0; off >>= 1){
        s  += __shfl_down(s,  off);
        s2 += __shfl_down(s2, off);
    }
    __shared__ float red[8];
    int wave = tid >> 6, lane = tid & 63;
    if (lane == 0){ red[wave*2] = s; red[wave*2+1] = s2; }
    __syncthreads();
    if (tid == 0){
        float S1 = 0.f, S2 = 0.f;
        for (int w = 0; w < 4; w++){ S1 += red[w*2]; S2 += red[w*2+1]; }
        const float inv = 1.f / (float)(SS * DMT);
        float m = S1 * inv;
        float var = S2 * inv - m * m;
        mu[tt*64 + j] = m;
        rs[tt*64 + j] = rsqrtf(var + EPSV);
    }
}

// ---------------- U = mean of 4 normalized tensors -> bf16 ----------------
__global__ __launch_bounds__(256) void build_u(const float* r1, const float* r2,
                                               const float* r3, const float* r4,
                                               const float* mu, const float* rs, u16* Ubf){
    int row = blockIdx.x;           // 0..16383 (= t*B + j)
    int j = row & 63;
    float m1 = mu[j],      s1 = rs[j];
    float m2 = mu[64+j],   s2 = rs[64+j];
    float m3 = mu[128+j],  s3 = rs[128+j];
    float m4 = mu[192+j],  s4 = rs[192+j];
    int c = threadIdx.x;
    const float4* p1 = (const float4*)(r1 + (size_t)row * DMT);
    const float4* p2 = (const float4*)(r2 + (size_t)row * DMT);
    const float4* p3 = (const float4*)(r3 + (size_t)row * DMT);
    const float4* p4 = (const float4*)(r4 + (size_t)row * DMT);
    float4 a = p1[c], b = p2[c], d = p3[c], e = p4[c];
    float ux = ((a.x-m1)*s1 + (b.x-m2)*s2 + (d.x-m3)*s3 + (e.x-m4)*s4) * 0.25f;
    float uy = ((a.y-m1)*s1 + (b.y-m2)*s2 + (d.y-m3)*s3 + (e.y-m4)*s4) * 0.25f;
    float uz = ((a.z-m1)*s1 + (b.z-m2)*s2 + (d.z-m3)*s3 + (e.z-m4)*s4) * 0.25f;
    float uw = ((a.w-m1)*s1 + (b.w-m2)*s2 + (d.w-m3)*s3 + (e.w-m4)*s4) * 0.25f;
    u16 o[4] = { f2bf(ux), f2bf(uy), f2bf(uz), f2bf(uw) };
    *(uint2*)(Ubf + (size_t)row * DMT + c*4) = *(uint2*)o;
}

// ---------------- casts ----------------
__global__ void cast_bf16(const float* in, u16* out, int n){
    int i4 = blockIdx.x * blockDim.x + threadIdx.x;
    int n4 = n >> 2;
    for (; i4 < n4; i4 += gridDim.x * blockDim.x){
        float4 v = ((const float4*)in)[i4];
        u16 o[4] = { f2bf(v.x), f2bf(v.y), f2bf(v.z), f2bf(v.w) };
        *(uint2*)(out + i4*4) = *(uint2*)o;
    }
}
__global__ void cast_f16(const float* in, u16* out, int n){
    int i4 = blockIdx.x * blockDim.x + threadIdx.x;
    int n4 = n >> 2;
    for (; i4 < n4; i4 += gridDim.x * blockDim.x){
        float4 v = ((const float4*)in)[i4];
        _Float16 h[4] = { (_Float16)v.x, (_Float16)v.y, (_Float16)v.z, (_Float16)v.w };
        *(uint2*)(out + i4*4) = *(uint2*)h;
    }
}

// ---------------- bf16 MFMA GEMM: C[M,N] = A[M,K] @ W[N,K]^T + bias ----------------
// Cf (f32, ld=N) and/or Cb (bf16, ld=ldcb, col offset coloff) outputs, either may be null.
__global__ __launch_bounds__(256) void gemm_bt(const u16* __restrict__ A,
                                               const u16* __restrict__ Bw,
                                               const float* __restrict__ bias,
                                               float* __restrict__ Cf, u16* __restrict__ Cb,
                                               int M, int N, int K, int ldcb, int coloff){
    __shared__ __align__(16) u16 As[128*40];
    __shared__ __align__(16) u16 Bs[128*40];
    int tid = threadIdx.x;
    int bm = blockIdx.y * 128, bn = blockIdx.x * 128;
    int wave = tid >> 6, lane = tid & 63;
    int wr = wave & 1, wc = wave >> 1;
    int lr = lane & 15, kq = (lane >> 4) * 8;
    v4f acc[4][4] = {};
    int nk = (K + 31) >> 5;
    for (int kt = 0; kt < nk; kt++){
        int k0 = kt << 5;
        #pragma unroll
        for (int s = 0; s < 2; s++){
            int seg = tid + (s << 8);
            int row = seg >> 2, ko = (seg & 3) << 3;
            int gk = k0 + ko;
            {
                const u16* src = A + (size_t)(bm + row) * K + gk;
                u16 t0[8];
                if (gk + 8 <= K){
                    uint2 u0 = *(const uint2*)src;
                    uint2 u1 = *(const uint2*)(src + 4);
                    *(uint2*)&t0[0] = u0; *(uint2*)&t0[4] = u1;
                } else {
                    #pragma unroll
                    for (int e = 0; e < 8; e++) t0[e] = (gk + e < K) ? src[e] : (u16)0;
                }
                *(uint4*)&As[row*40 + ko] = *(uint4*)t0;
            }
            {
                const u16* src = Bw + (size_t)(bn + row) * K + gk;
                u16 t0[8];
                if (gk + 8 <= K){
                    uint2 u0 = *(const uint2*)src;
                    uint2 u1 = *(const uint2*)(src + 4);
                    *(uint2*)&t0[0] = u0; *(uint2*)&t0[4] = u1;
                } else {
                    #pragma unroll
                    for (int e = 0; e < 8; e++) t0[e] = (gk + e < K) ? src[e] : (u16)0;
                }
                *(uint4*)&Bs[row*40 + ko] = *(uint4*)t0;
            }
        }
        __syncthreads();
        v8s af[4], bfr[4];
        #pragma unroll
        for (int i = 0; i < 4; i++) af[i]  = *(const v8s*)&As[(wr*64 + i*16 + lr)*40 + kq];
        #pragma unroll
        for (int j = 0; j < 4; j++) bfr[j] = *(const v8s*)&Bs[(wc*64 + j*16 + lr)*40 + kq];
        #pragma unroll
        for (int i = 0; i < 4; i++)
            #pragma unroll
            for (int j = 0; j < 4; j++)
                acc[i][j] = __builtin_amdgcn_mfma_f32_16x16x32_bf16(af[i], bfr[j], acc[i][j], 0, 0, 0);
        __syncthreads();
    }
    int quad = lane >> 4;
    #pragma unroll
    for (int i = 0; i < 4; i++){
        #pragma unroll
        for (int j = 0; j < 4; j++){
            int col = bn + wc*64 + j*16 + lr;
            float bv = bias ? bias[col] : 0.f;
            #pragma unroll
            for (int r = 0; r < 4; r++){
                int rowg = bm + wr*64 + i*16 + quad*4 + r;
                float v = acc[i][j][r] + bv;
                if (Cf) Cf[(size_t)rowg * N + col] = v;
                if (Cb) Cb[(size_t)rowg * ldcb + coloff + col] = f2bf(v);
            }
        }
    }
}

// ---------------- LSTM layer (both directions), sample-per-block, no inter-block sync ----------
// Xg*: [S*B, 1024] precomputed x@Wih^T + b. WhhL: f16 [2][1024][256] for this layer.
// Output h (bf16) at Hout[row*ldo + dir*256 + n].
//
// Weight tiering per gate row (256 f16 values), chosen so NOTHING spills:
//   values [  0,152) : 76 u32 in VGPRs          (launch_bounds(1024,4) -> 128-VGPR cap)
//   values [152,208) : 56 values in LDS, 112B/row, stride = 7x16B (odd multiple of 16B
//                      -> b128 reads cycle all 32 banks per 8 lanes: conflict-free)
//   values [208,256) : 48 values streamed from L1/L2 each step (96B/thread)
// LDS total: 112KB weights + 512B h + 4KB gates = 116.5KB (< 160KB, 1 block/CU).
__global__ __launch_bounds__(1024, 4) void lstm_layer(const float* __restrict__ Xgf,
                                                      const float* __restrict__ Xgb,
                                                      const u16* __restrict__ WhhL,
                                                      u16* __restrict__ Hout, int ldo){
    int dir = blockIdx.x & 1;
    int j   = blockIdx.x >> 1;
    int tid = threadIdx.x;            // gate row 0..1023
    const float* Xg = dir ? Xgb : Xgf;
    const uint4* wp = (const uint4*)(WhhL + ((size_t)(dir*1024 + tid)) * 256);

    // tier 1: values [0,152) of this thread's Whh row -> 19 uint4 = 76 u32 in registers
    u32 w[76];
    #pragma unroll
    for (int q = 0; q < 19; q++){
        uint4 v = wp[q];
        w[q*4+0] = v.x; w[q*4+1] = v.y; w[q*4+2] = v.z; w[q*4+3] = v.w;
    }

    // tier 2: values [152,208) -> LDS, 7 uint4 per row, stride 112B (conflict-free)
    __shared__ __align__(16) u32 wl[1024][28];
    #pragma unroll
    for (int q = 0; q < 7; q++){
        ((uint4*)wl[tid])[q] = wp[19 + q];
    }

    __shared__ __align__(16) u16 hsh[256];   // h_{t-1} as f16
    __shared__ float gsh[1024];
    if (tid < 256) hsh[tid] = 0;
    float c = 0.f;
    __syncthreads();

    int coloff = dir * 256;
    for (int step = 0; step < SS; step++){
        int t = dir ? (SS - 1 - step) : step;
        int row = t * BB + j;
        float gv = Xg[(size_t)row * 1024 + tid];

        float acc = 0.f;
        const uint4* hp = (const uint4*)hsh;

        // tier 1: register-resident weights vs h[0..151]
        #pragma unroll
        for (int q = 0; q < 19; q++){
            uint4 hv = hp[q];                       // broadcast LDS read
            acc = dot2u(hv.x, w[q*4+0], acc);
            acc = dot2u(hv.y, w[q*4+1], acc);
            acc = dot2u(hv.z, w[q*4+2], acc);
            acc = dot2u(hv.w, w[q*4+3], acc);
        }
        // tier 2: LDS-resident weights vs h[152..207]
        #pragma unroll
        for (int q = 0; q < 7; q++){
            uint4 hv = hp[19 + q];
            uint4 wv = ((const uint4*)wl[tid])[q];  // private LDS read, conflict-free
            acc = dot2u(hv.x, wv.x, acc);
            acc = dot2u(hv.y, wv.y, acc);
            acc = dot2u(hv.z, wv.z, acc);
            acc = dot2u(hv.w, wv.w, acc);
        }
        // tier 3: streamed weights vs h[208..255]
        #pragma unroll
        for (int q = 0; q < 6; q++){
            uint4 hv = hp[26 + q];
            uint4 wv = wp[26 + q];                  // streamed from L1/L2 each step
            acc = dot2u(hv.x, wv.x, acc);
            acc = dot2u(hv.y, wv.y, acc);
            acc = dot2u(hv.z, wv.z, acc);
            acc = dot2u(hv.w, wv.w, acc);
        }
        gsh[tid] = gv + acc;
        __syncthreads();
        if (tid < 256){
            float gi = sigm(gsh[tid]);
            float gf = sigm(gsh[256 + tid]);
            float gg = tanhf(gsh[512 + tid]);
            float go = sigm(gsh[768 + tid]);
            c = gf * c + gi * gg;
            float h = go * tanhf(c);
            hsh[tid] = __builtin_bit_cast(u16, (_Float16)h);
            Hout[(size_t)row * ldo + coloff + tid] = f2bf(h);
        }
        __syncthreads();
    }
}

// ---------------- final ragged gather / concat ----------------
__global__ __launch_bounds__(256) void gather_out(const u16* __restrict__ Xu,
                                                  const float* __restrict__ Fused,
                                                  const float* __restrict__ r2,
                                                  const float* __restrict__ mu,
                                                  const float* __restrict__ rs,
                                                  const float* __restrict__ Ua,
                                                  const float* __restrict__ Uv,
                                                  const int* __restrict__ idx,
                                                  float* __restrict__ outp){
    int i = blockIdx.x;
    int src = idx[i];
    int j = src & 63;
    float m2 = mu[64 + j], s2v = rs[64 + j];
    float* o = outp + (size_t)i * OUTW;
    const u16* xr = Xu + (size_t)src * 1536;
    const float* fr = Fused + (size_t)src * 512;
    const float* rr = r2 + (size_t)src * 1024;
    const float* ar = Ua + (size_t)src * 100;
    const float* vr = Uv + (size_t)src * 512;
    for (int c = threadIdx.x; c < 1536; c += 256) o[c] = bf2f(xr[c]);          // f_l | f_a | f_v
    for (int c = threadIdx.x; c < 512;  c += 256) o[1536 + c] = fr[c];         // f_u
    for (int c = threadIdx.x; c < 1024; c += 256) o[2048 + c] = (rr[c] - m2) * s2v; // LN(r2)
    for (int c = threadIdx.x; c < 100;  c += 256) o[3072 + c] = ar[c];         // U_a raw
    for (int c = threadIdx.x; c < 512;  c += 256) o[3172 + c] = vr[c];         // U_v raw
}

extern "C" void kernel_launch(void* const* d_in, const int* in_sizes, int n_in,
                              void* d_out, int out_size, void* d_ws, size_t ws_size,
                              hipStream_t stream){
    const float* r1 = (const float*)d_in[0];
    const float* r2 = (const float*)d_in[1];
    const float* r3 = (const float*)d_in[2];
    const float* r4 = (const float*)d_in[3];
    const float* U_a = (const float*)d_in[5];
    const float* U_v = (const float*)d_in[6];
    const float* W_a = (const float*)d_in[7];
    const float* b_a = (const float*)d_in[8];
    const float* W_v = (const float*)d_in[9];
    const float* b_v = (const float*)d_in[10];
    const float* W_l = (const float*)d_in[11];
    const float* b_l = (const float*)d_in[12];
    const float* Wih = (const float*)d_in[13];
    const float* Whh = (const float*)d_in[14];
    const float* lb  = (const float*)d_in[15];
    const float* W_u = (const float*)d_in[16];
    const float* b_u = (const float*)d_in[17];
    const int* nidx  = (const int*)d_in[18];
    float* outp = (float*)d_out;

    char* p = (char*)d_ws;
    auto alloc = [&](size_t bytes){ char* r = p; p += (bytes + 255) & ~(size_t)255; return r; };
    float* mu   = (float*)alloc(256 * 4);
    float* rs   = (float*)alloc(256 * 4);
    u16* Ubf    = (u16*)alloc((size_t)NROWS * DMT * 2);
    u16* Uabf   = (u16*)alloc((size_t)NROWS * DMA * 2);
    u16* Uvbf   = (u16*)alloc((size_t)NROWS * DMV * 2);
    u16* Wlbf   = (u16*)alloc((size_t)DG * DMT * 2);
    u16* Wabf   = (u16*)alloc((size_t)DG * DMA * 2);
    u16* Wvbf   = (u16*)alloc((size_t)DG * DMV * 2);
    u16* Wubf   = (u16*)alloc((size_t)DG * 3 * DG * 2);
    u16* Wihbf  = (u16*)alloc((size_t)4 * 1024 * 512 * 2);
    u16* Whhf   = (u16*)alloc((size_t)4 * 1024 * 256 * 2);
    u16* Xlbf   = (u16*)alloc((size_t)NROWS * DG * 2);
    float* Xgf  = (float*)alloc((size_t)NROWS * 1024 * 4);
    float* Xgb  = (float*)alloc((size_t)NROWS * 1024 * 4);
    u16* L0bf   = (u16*)alloc((size_t)NROWS * DG * 2);
    u16* Xubf   = (u16*)alloc((size_t)NROWS * 1536 * 2);
    float* Fus  = (float*)alloc((size_t)NROWS * DG * 4);

    // 1) LN stats + U
    ln_stats<<<dim3(64, 4), 256, 0, stream>>>(r1, r2, r3, r4, mu, rs);
    build_u<<<NROWS, 256, 0, stream>>>(r1, r2, r3, r4, mu, rs, Ubf);

    // 2) casts
    cast_bf16<<<1024, 256, 0, stream>>>(U_a, Uabf, NROWS * DMA);
    cast_bf16<<<1024, 256, 0, stream>>>(U_v, Uvbf, NROWS * DMV);
    cast_bf16<<<64, 256, 0, stream>>>(W_a, Wabf, DG * DMA);
    cast_bf16<<<128, 256, 0, stream>>>(W_v, Wvbf, DG * DMV);
    cast_bf16<<<256, 256, 0, stream>>>(W_l, Wlbf, DG * DMT);
    cast_bf16<<<256, 256, 0, stream>>>(W_u, Wubf, DG * 3 * DG);
    cast_bf16<<<512, 256, 0, stream>>>(Wih, Wihbf, 4 * 1024 * 512);
    cast_f16<<<512, 256, 0, stream>>>(Whh, Whhf, 4 * 1024 * 256);

    // 3) projections
    // Xl = U @ W_l^T + b_l  -> bf16
    gemm_bt<<<dim3(DG/128, NROWS/128), 256, 0, stream>>>(Ubf, Wlbf, b_l, nullptr, Xlbf,
                                                         NROWS, DG, DMT, DG, 0);
    // Ea -> Xu[:,512:1024) bf16
    gemm_bt<<<dim3(DG/128, NROWS/128), 256, 0, stream>>>(Uabf, Wabf, b_a, nullptr, Xubf,
                                                         NROWS, DG, DMA, 1536, 512);
    // Ev -> Xu[:,1024:1536) bf16
    gemm_bt<<<dim3(DG/128, NROWS/128), 256, 0, stream>>>(Uvbf, Wvbf, b_v, nullptr, Xubf,
                                                         NROWS, DG, DMV, 1536, 1024);

    // 4) layer 0 input gates
    gemm_bt<<<dim3(1024/128, NROWS/128), 256, 0, stream>>>(Xlbf, Wihbf, lb, Xgf, nullptr,
                                                           NROWS, 1024, 512, 0, 0);
    gemm_bt<<<dim3(1024/128, NROWS/128), 256, 0, stream>>>(Xlbf, Wihbf + (size_t)1024*512, lb + 1024,
                                                           Xgb, nullptr, NROWS, 1024, 512, 0, 0);
    // 5) layer 0 recurrence -> L0bf [16384,512]
    lstm_layer<<<128, 1024, 0, stream>>>(Xgf, Xgb, Whhf, L0bf, 512);

    // 6) layer 1 input gates
    gemm_bt<<<dim3(1024/128, NROWS/128), 256, 0, stream>>>(L0bf, Wihbf + (size_t)2*1024*512, lb + 2048,
                                                           Xgf, nullptr, NROWS, 1024, 512, 0, 0);
    gemm_bt<<<dim3(1024/128, NROWS/128), 256, 0, stream>>>(L0bf, Wihbf + (size_t)3*1024*512, lb + 3072,
                                                           Xgb, nullptr, NROWS, 1024, 512, 0, 0);
    // 7) layer 1 recurrence -> Xu[:,0:512) bf16
    lstm_layer<<<128, 1024, 0, stream>>>(Xgf, Xgb, Whhf + (size_t)2*1024*256, Xubf, 1536);

    // 8) fusion GEMM: Fused = Xu @ W_u^T + b_u (f32)
    gemm_bt<<<dim3(DG/128, NROWS/128), 256, 0, stream>>>(Xubf, Wubf, b_u, Fus, nullptr,
                                                         NROWS, DG, 3*DG, 0, 0);

    // 9) gather
    int N = out_size / OUTW;
    gather_out<<<N, 256, 0, stream>>>(Xubf, Fus, r2, mu, rs, U_a, U_v, nidx, outp);
}